// Round 5
// baseline (31.278 us; speedup 1.0000x reference)
//
#include <hip/hip_runtime.h>

#define NB 64
#define NA 5
#define NC 20
#define NH 38
#define NW 38
#define MAXT 40
#define CS (NH * NW)                 // 1444
#define CELLS_PER_B (NA * CS)        // 7220
#define TPB 256
#define CPT 4                        // cells per thread
#define CHUNK_CELLS (TPB * CPT)      // 1024
#define CHUNKS 8                     // ceil(7220 / 1024)

__constant__ float c_aw[NA] = {1.3221f, 3.19275f, 5.05587f, 9.47112f, 11.2364f};
__constant__ float c_ah[NA] = {1.73145f, 4.00944f, 8.09892f, 4.84053f, 10.0071f};

__device__ __forceinline__ float sl1(float d) {
    d = fabsf(d);
    return (d < 1.0f) ? 0.5f * d * d : d - 0.5f;
}
__device__ __forceinline__ float sigm(float x) {
    return __builtin_amdgcn_rcpf(1.0f + __expf(-x));
}

// ---------------- prep: targets -> packed global, winner pass, zero d_out ----
__global__ __launch_bounds__(64) void prep_kernel(
    const float* __restrict__ outp, const float* __restrict__ tgt,
    float4* __restrict__ boxes,   // [NB*MAXT] x1,y1,x2,y2
    float*  __restrict__ gas,     // [NB*MAXT] 0.4*gw*gh
    float2* __restrict__ winner,  // [NB] {box_corr, cls}
    float*  __restrict__ o)
{
    const int b   = blockIdx.x;
    const int tid = threadIdx.x;           // one wave
    if (b == 0 && tid < 3) o[tid] = 0.0f;  // runs before dense dispatch

    __shared__ float4 s_box[MAXT];
    __shared__ float  s_ga[MAXT];
    __shared__ int    s_key[MAXT];

    const bool is_t = tid < MAXT;
    const float* tb = tgt + b * (MAXT * 5) + tid * 5;
    float t0 = 0.f, t1 = 0.f, t2 = 0.f, t3 = 0.f, t4 = 0.f;
    if (is_t) { t0 = tb[0]; t1 = tb[1]; t2 = tb[2]; t3 = tb[3]; t4 = tb[4]; }
    const unsigned long long nz = __ballot(is_t && (t1 != 0.0f));
    const bool valid = is_t && ((~nz & (((1ull << tid) << 1) - 1ull)) == 0ull);

    float w_gx = 0.f, w_gy = 0.f, w_gw = 0.f, w_gh = 0.f;
    int   w_bn = 0, w_gi = 0, w_gj = 0, w_cls = 0, mykey = -1;

    if (is_t) {
        float4 mybox = make_float4(3e30f, 3e30f, -3e30f, -3e30f);
        float  myga  = 0.0f;
        if (valid) {
            const float gx = t1 * NW, gy = t2 * NH, gw = t3 * NW, gh = t4 * NH;
            int bn = 0; float best = -1.0f;
            #pragma unroll
            for (int a = 0; a < NA; ++a) {
                const float inter = fminf(gw, c_aw[a]) * fminf(gh, c_ah[a]);
                const float aiou  = inter / (gw * gh + c_aw[a] * c_ah[a] - inter);
                if (aiou > best) { best = aiou; bn = a; }
            }
            const int gi = min(max((int)gx, 0), NW - 1);
            const int gj = min(max((int)gy, 0), NH - 1);
            mybox = make_float4(gx - 0.5f * gw, gy - 0.5f * gh,
                                gx + 0.5f * gw, gy + 0.5f * gh);
            myga  = 0.4f * gw * gh;
            mykey = bn * CS + gj * NW + gi;
            w_gx = gx; w_gy = gy; w_gw = gw; w_gh = gh;
            w_bn = bn; w_gi = gi; w_gj = gj; w_cls = (int)t0;
        }
        s_box[tid] = mybox; s_ga[tid] = myga; s_key[tid] = valid ? mykey : -1;
        boxes[b * MAXT + tid] = mybox;
        gas[b * MAXT + tid]   = myga;
    }
    __syncthreads();

    float box_sum = 0.0f, cls_sum = 0.0f;
    if (valid) {
        bool last = true;
        for (int tp = tid + 1; tp < MAXT; ++tp) last &= (s_key[tp] != mykey);
        if (last) {
            const float* cell = outp + (size_t)((b * NA + w_bn) * (5 + NC)) * CS
                                + (w_gj * NW + w_gi);
            const float xo = cell[0],      yo = cell[CS];
            const float wo = cell[2 * CS], ho = cell[3 * CS], co = cell[4 * CS];
            float cls_v[NC];
            #pragma unroll
            for (int q = 0; q < NC; ++q) cls_v[q] = cell[(5 + q) * CS];

            const float sx = sigm(xo), sy = sigm(yo), sc = sigm(co);
            const float pxc = sx + (float)w_gi, pyc = sy + (float)w_gj;
            const float pw = __expf(wo) * c_aw[w_bn], ph = __expf(ho) * c_ah[w_bn];
            const float px1 = pxc - 0.5f * pw, px2 = pxc + 0.5f * pw;
            const float py1 = pyc - 0.5f * ph, py2 = pyc + 0.5f * ph;
            const float pa = pw * ph, p04 = 0.4f * pa;

            // flag exactly as the dense thread computes it (same values/order)
            bool flag = false;
            for (int t = 0; t < MAXT; ++t) {
                const float4 bx = s_box[t];
                const float iw = fminf(px2, bx.z) - fmaxf(px1, bx.x);
                const float ih = fminf(py2, bx.w) - fmaxf(py1, bx.y);
                const float inter = fmaxf(iw, 0.0f) * fmaxf(ih, 0.0f);
                flag = flag | (1.4f * inter > p04 + s_ga[t]);
            }
            const float cmd = flag ? 0.0f : 1.0f;

            // tconf = IoU(own gt, pred), exact divide
            const float gx1 = w_gx - 0.5f * w_gw, gx2 = w_gx + 0.5f * w_gw;
            const float gy1 = w_gy - 0.5f * w_gh, gy2 = w_gy + 0.5f * w_gh;
            const float iw = fminf(px2, gx2) - fmaxf(px1, gx1);
            const float ih = fminf(py2, gy2) - fmaxf(py1, gy1);
            const float inter = fmaxf(iw, 0.f) * fmaxf(ih, 0.f);
            const float tconf = inter / (w_gw * w_gh + pa - inter);

            const float dc = sc - tconf;
            box_sum += 2.5f * dc * dc - 0.5f * cmd * sc * sc;  // winner - dense term

            const float vtx = w_gx - (float)w_gi, vty = w_gy - (float)w_gj;
            const float vtw = __logf(w_gw / c_aw[w_bn]);
            const float vth = __logf(w_gh / c_ah[w_bn]);
            box_sum += 0.5f * (sl1(sx - vtx) + sl1(sy - vty) +
                               sl1(wo - vtw) + sl1(ho - vth));

            float m = -1e30f;
            #pragma unroll
            for (int q = 0; q < NC; ++q) m = fmaxf(m, cls_v[q]);
            float se = 0.f, lt = 0.f;
            #pragma unroll
            for (int q = 0; q < NC; ++q) {
                se += __expf(cls_v[q] - m);
                if (q == w_cls) lt = cls_v[q];
            }
            const float logpt = lt - (m + __logf(se));
            const float pt = __expf(logpt);
            const float om = 1.0f - pt;
            cls_sum += -(om * om) * logpt;
        }
    }

    #pragma unroll
    for (int off = 32; off > 0; off >>= 1) {
        box_sum += __shfl_down(box_sum, off);
        cls_sum += __shfl_down(cls_sum, off);
    }
    if (tid == 0) winner[b] = make_float2(box_sum, cls_sum);
}

// ---------------- dense: pure conf-loss pass, targets via scalar loads --------
__global__ __launch_bounds__(TPB) void dense_kernel(
    const float* __restrict__ outp,
    const float4* __restrict__ boxes, const float* __restrict__ gas,
    const float2* __restrict__ winner, float* __restrict__ o)
{
    const int b     = blockIdx.x / CHUNKS;
    const int chunk = blockIdx.x - b * CHUNKS;
    const int tid   = threadIdx.x;
    const float4* bb = boxes + b * MAXT;   // block-uniform base -> s_load
    const float*  gg = gas   + b * MAXT;

    const int cbase = chunk * CHUNK_CELLS + tid;
    float px1[CPT], px2[CPT], py1[CPT], py2[CPT], p04[CPT], scv[CPT];
    bool  flag[CPT];

    #pragma unroll
    for (int u = 0; u < CPT; ++u) {
        const int c = cbase + u * TPB;
        flag[u] = false;
        if (c < CELLS_PER_B) {
            const int a = c / CS, r = c - a * CS;
            const int j = r / NW,  i = r - j * NW;
            const float* cell = outp + (size_t)((b * NA + a) * (5 + NC)) * CS + r;
            const float xo = cell[0],      yo = cell[CS];
            const float wo = cell[2 * CS], ho = cell[3 * CS], co = cell[4 * CS];
            const float sx = sigm(xo), sy = sigm(yo);
            scv[u] = sigm(co);
            const float pxc = sx + (float)i, pyc = sy + (float)j;
            const float pw = __expf(wo) * c_aw[a], ph = __expf(ho) * c_ah[a];
            px1[u] = pxc - 0.5f * pw; px2[u] = pxc + 0.5f * pw;
            py1[u] = pyc - 0.5f * ph; py2[u] = pyc + 0.5f * ph;
            p04[u] = 0.4f * (pw * ph);
        } else {
            px1[u] = 3e30f; px2[u] = -3e30f;   // inter -> 0, flag stays false
            py1[u] = 3e30f; py2[u] = -3e30f;
            p04[u] = 0.0f;  scv[u] = 0.0f;     // contribution -> 0
        }
    }

    #pragma unroll 8
    for (int t = 0; t < MAXT; ++t) {
        const float4 bx = bb[t];     // uniform -> SGPR broadcast
        const float  ga = gg[t];
        #pragma unroll
        for (int u = 0; u < CPT; ++u) {
            const float iw = fminf(px2[u], bx.z) - fmaxf(px1[u], bx.x);
            const float ih = fminf(py2[u], bx.w) - fmaxf(py1[u], bx.y);
            const float inter = fmaxf(iw, 0.0f) * fmaxf(ih, 0.0f);
            flag[u] = flag[u] | (1.4f * inter > p04[u] + ga);
        }
    }

    float box_sum = 0.0f;
    #pragma unroll
    for (int u = 0; u < CPT; ++u) {
        const float cm = flag[u] ? 0.0f : 1.0f;
        box_sum += 0.5f * cm * scv[u] * scv[u];
    }

    #pragma unroll
    for (int off = 32; off > 0; off >>= 1) box_sum += __shfl_down(box_sum, off);
    __shared__ float red[4];
    const int wv = tid >> 6, ln = tid & 63;
    if (ln == 0) red[wv] = box_sum;
    __syncthreads();
    if (tid == 0) {
        float box = red[0] + red[1] + red[2] + red[3];
        float cls = 0.0f;
        if (chunk == 0) {
            const float2 wn = winner[b];
            box += wn.x; cls = wn.y;
            atomicAdd(&o[1], cls);
        }
        atomicAdd(&o[0], box + cls);
        atomicAdd(&o[2], box);
    }
}

extern "C" void kernel_launch(void* const* d_in, const int* in_sizes, int n_in,
                              void* d_out, int out_size, void* d_ws, size_t ws_size,
                              hipStream_t stream)
{
    const float* outp = (const float*)d_in[0];
    const float* tgt  = (const float*)d_in[1];
    float* o = (float*)d_out;

    char* ws = (char*)d_ws;
    float2* winner = (float2*)ws;                      // 512 B
    float4* boxes  = (float4*)(ws + 1024);             // 40 KiB
    float*  gas    = (float*)(ws + 1024 + NB * MAXT * sizeof(float4));

    prep_kernel<<<dim3(NB), dim3(64), 0, stream>>>(outp, tgt, boxes, gas, winner, o);
    dense_kernel<<<dim3(NB * CHUNKS), dim3(TPB), 0, stream>>>(outp, boxes, gas, winner, o);
}

// Round 6
// 23.634 us; speedup vs baseline: 1.3234x; 1.3234x over previous
//
#include <hip/hip_runtime.h>

#define NB 64
#define NA 5
#define NC 20
#define NH 38
#define NW 38
#define MAXT 40
#define CS (NH * NW)                 // 1444
#define CELLS_PER_B (NA * CS)        // 7220
#define TPB 256
#define CPT 4                        // cells per thread
#define CHUNK_CELLS (TPB * CPT)      // 1024
#define CHUNKS 8                     // ceil(7220 / 1024)
#define NPART (NB * CHUNKS)          // 512 dense blocks

__constant__ float c_aw[NA] = {1.3221f, 3.19275f, 5.05587f, 9.47112f, 11.2364f};
__constant__ float c_ah[NA] = {1.73145f, 4.00944f, 8.09892f, 4.84053f, 10.0071f};

__device__ __forceinline__ float sl1(float d) {
    d = fabsf(d);
    return (d < 1.0f) ? 0.5f * d * d : d - 0.5f;
}
__device__ __forceinline__ float sigm(float x) {
    return __builtin_amdgcn_rcpf(1.0f + __expf(-x));
}

// ---------------- prep: targets -> packed global + winner pass ---------------
__global__ __launch_bounds__(64) void prep_kernel(
    const float* __restrict__ outp, const float* __restrict__ tgt,
    float4* __restrict__ boxes,   // [NB*MAXT] x1,y1,x2,y2
    float*  __restrict__ gas,     // [NB*MAXT] 0.4*gw*gh
    float2* __restrict__ winner)  // [NB] {box_corr, cls}
{
    const int b   = blockIdx.x;
    const int tid = threadIdx.x;           // one wave

    __shared__ float4 s_box[MAXT];
    __shared__ float  s_ga[MAXT];
    __shared__ int    s_key[MAXT];

    const bool is_t = tid < MAXT;
    const float* tb = tgt + b * (MAXT * 5) + tid * 5;
    float t0 = 0.f, t1 = 0.f, t2 = 0.f, t3 = 0.f, t4 = 0.f;
    if (is_t) { t0 = tb[0]; t1 = tb[1]; t2 = tb[2]; t3 = tb[3]; t4 = tb[4]; }
    const unsigned long long nz = __ballot(is_t && (t1 != 0.0f));
    const bool valid = is_t && ((~nz & (((1ull << tid) << 1) - 1ull)) == 0ull);

    float w_gx = 0.f, w_gy = 0.f, w_gw = 0.f, w_gh = 0.f;
    int   w_bn = 0, w_gi = 0, w_gj = 0, w_cls = 0, mykey = -1;

    if (is_t) {
        float4 mybox = make_float4(3e30f, 3e30f, -3e30f, -3e30f);
        float  myga  = 0.0f;
        if (valid) {
            const float gx = t1 * NW, gy = t2 * NH, gw = t3 * NW, gh = t4 * NH;
            int bn = 0; float best = -1.0f;
            #pragma unroll
            for (int a = 0; a < NA; ++a) {
                const float inter = fminf(gw, c_aw[a]) * fminf(gh, c_ah[a]);
                const float aiou  = inter / (gw * gh + c_aw[a] * c_ah[a] - inter);
                if (aiou > best) { best = aiou; bn = a; }
            }
            const int gi = min(max((int)gx, 0), NW - 1);
            const int gj = min(max((int)gy, 0), NH - 1);
            mybox = make_float4(gx - 0.5f * gw, gy - 0.5f * gh,
                                gx + 0.5f * gw, gy + 0.5f * gh);
            myga  = 0.4f * gw * gh;
            mykey = bn * CS + gj * NW + gi;
            w_gx = gx; w_gy = gy; w_gw = gw; w_gh = gh;
            w_bn = bn; w_gi = gi; w_gj = gj; w_cls = (int)t0;
        }
        s_box[tid] = mybox; s_ga[tid] = myga; s_key[tid] = valid ? mykey : -1;
        boxes[b * MAXT + tid] = mybox;
        gas[b * MAXT + tid]   = myga;
    }
    __syncthreads();

    float box_sum = 0.0f, cls_sum = 0.0f;
    if (valid) {
        bool last = true;
        for (int tp = tid + 1; tp < MAXT; ++tp) last &= (s_key[tp] != mykey);
        if (last) {
            const float* cell = outp + (size_t)((b * NA + w_bn) * (5 + NC)) * CS
                                + (w_gj * NW + w_gi);
            const float xo = cell[0],      yo = cell[CS];
            const float wo = cell[2 * CS], ho = cell[3 * CS], co = cell[4 * CS];
            float cls_v[NC];
            #pragma unroll
            for (int q = 0; q < NC; ++q) cls_v[q] = cell[(5 + q) * CS];

            const float sx = sigm(xo), sy = sigm(yo), sc = sigm(co);
            const float pxc = sx + (float)w_gi, pyc = sy + (float)w_gj;
            const float pw = __expf(wo) * c_aw[w_bn], ph = __expf(ho) * c_ah[w_bn];
            const float px1 = pxc - 0.5f * pw, px2 = pxc + 0.5f * pw;
            const float py1 = pyc - 0.5f * ph, py2 = pyc + 0.5f * ph;
            const float pa = pw * ph, p04 = 0.4f * pa;

            // flag exactly as the dense thread computes it (same values/order)
            bool flag = false;
            for (int t = 0; t < MAXT; ++t) {
                const float4 bx = s_box[t];
                const float iw = fminf(px2, bx.z) - fmaxf(px1, bx.x);
                const float ih = fminf(py2, bx.w) - fmaxf(py1, bx.y);
                const float inter = fmaxf(iw, 0.0f) * fmaxf(ih, 0.0f);
                flag = flag | (1.4f * inter > p04 + s_ga[t]);
            }
            const float cmd = flag ? 0.0f : 1.0f;

            // tconf = IoU(own gt, pred), exact divide
            const float gx1 = w_gx - 0.5f * w_gw, gx2 = w_gx + 0.5f * w_gw;
            const float gy1 = w_gy - 0.5f * w_gh, gy2 = w_gy + 0.5f * w_gh;
            const float iw = fminf(px2, gx2) - fmaxf(px1, gx1);
            const float ih = fminf(py2, gy2) - fmaxf(py1, gy1);
            const float inter = fmaxf(iw, 0.f) * fmaxf(ih, 0.f);
            const float tconf = inter / (w_gw * w_gh + pa - inter);

            const float dc = sc - tconf;
            box_sum += 2.5f * dc * dc - 0.5f * cmd * sc * sc;  // winner - dense term

            const float vtx = w_gx - (float)w_gi, vty = w_gy - (float)w_gj;
            const float vtw = __logf(w_gw / c_aw[w_bn]);
            const float vth = __logf(w_gh / c_ah[w_bn]);
            box_sum += 0.5f * (sl1(sx - vtx) + sl1(sy - vty) +
                               sl1(wo - vtw) + sl1(ho - vth));

            float m = -1e30f;
            #pragma unroll
            for (int q = 0; q < NC; ++q) m = fmaxf(m, cls_v[q]);
            float se = 0.f, lt = 0.f;
            #pragma unroll
            for (int q = 0; q < NC; ++q) {
                se += __expf(cls_v[q] - m);
                if (q == w_cls) lt = cls_v[q];
            }
            const float logpt = lt - (m + __logf(se));
            const float pt = __expf(logpt);
            const float om = 1.0f - pt;
            cls_sum += -(om * om) * logpt;
        }
    }

    #pragma unroll
    for (int off = 32; off > 0; off >>= 1) {
        box_sum += __shfl_down(box_sum, off);
        cls_sum += __shfl_down(cls_sum, off);
    }
    if (tid == 0) winner[b] = make_float2(box_sum, cls_sum);
}

// ---------------- dense: pure conf-loss pass, per-block partial sums ---------
__global__ __launch_bounds__(TPB) void dense_kernel(
    const float* __restrict__ outp,
    const float4* __restrict__ boxes, const float* __restrict__ gas,
    float* __restrict__ partials)
{
    const int b     = blockIdx.x / CHUNKS;
    const int chunk = blockIdx.x - b * CHUNKS;
    const int tid   = threadIdx.x;
    const float4* bb = boxes + b * MAXT;   // block-uniform base -> s_load
    const float*  gg = gas   + b * MAXT;

    const int cbase = chunk * CHUNK_CELLS + tid;
    float px1[CPT], px2[CPT], py1[CPT], py2[CPT], p04[CPT], scv[CPT];
    bool  flag[CPT];

    #pragma unroll
    for (int u = 0; u < CPT; ++u) {
        const int c = cbase + u * TPB;
        flag[u] = false;
        if (c < CELLS_PER_B) {
            const int a = c / CS, r = c - a * CS;
            const int j = r / NW,  i = r - j * NW;
            const float* cell = outp + (size_t)((b * NA + a) * (5 + NC)) * CS + r;
            const float xo = cell[0],      yo = cell[CS];
            const float wo = cell[2 * CS], ho = cell[3 * CS], co = cell[4 * CS];
            const float sx = sigm(xo), sy = sigm(yo);
            scv[u] = sigm(co);
            const float pxc = sx + (float)i, pyc = sy + (float)j;
            const float pw = __expf(wo) * c_aw[a], ph = __expf(ho) * c_ah[a];
            px1[u] = pxc - 0.5f * pw; px2[u] = pxc + 0.5f * pw;
            py1[u] = pyc - 0.5f * ph; py2[u] = pyc + 0.5f * ph;
            p04[u] = 0.4f * (pw * ph);
        } else {
            px1[u] = 3e30f; px2[u] = -3e30f;   // inter -> 0, flag stays false
            py1[u] = 3e30f; py2[u] = -3e30f;
            p04[u] = 0.0f;  scv[u] = 0.0f;     // contribution -> 0
        }
    }

    #pragma unroll 8
    for (int t = 0; t < MAXT; ++t) {
        const float4 bx = bb[t];     // uniform -> SGPR broadcast
        const float  ga = gg[t];
        #pragma unroll
        for (int u = 0; u < CPT; ++u) {
            const float iw = fminf(px2[u], bx.z) - fmaxf(px1[u], bx.x);
            const float ih = fminf(py2[u], bx.w) - fmaxf(py1[u], bx.y);
            const float inter = fmaxf(iw, 0.0f) * fmaxf(ih, 0.0f);
            flag[u] = flag[u] | (1.4f * inter > p04[u] + ga);
        }
    }

    float box_sum = 0.0f;
    #pragma unroll
    for (int u = 0; u < CPT; ++u) {
        const float cm = flag[u] ? 0.0f : 1.0f;
        box_sum += 0.5f * cm * scv[u] * scv[u];
    }

    #pragma unroll
    for (int off = 32; off > 0; off >>= 1) box_sum += __shfl_down(box_sum, off);
    __shared__ float red[4];
    const int wv = tid >> 6, ln = tid & 63;
    if (ln == 0) red[wv] = box_sum;
    __syncthreads();
    if (tid == 0) partials[blockIdx.x] = red[0] + red[1] + red[2] + red[3];
}

// ---------------- finalize: reduce partials + winners, write d_out -----------
__global__ __launch_bounds__(256) void finalize_kernel(
    const float* __restrict__ partials, const float2* __restrict__ winner,
    float* __restrict__ o)
{
    const int tid = threadIdx.x;
    float box = partials[tid] + partials[tid + 256];   // NPART == 512
    float cls = 0.0f;
    if (tid < NB) {
        const float2 w = winner[tid];
        box += w.x; cls = w.y;
    }
    #pragma unroll
    for (int off = 32; off > 0; off >>= 1) {
        box += __shfl_down(box, off);
        cls += __shfl_down(cls, off);
    }
    __shared__ float red[8];
    const int wv = tid >> 6, ln = tid & 63;
    if (ln == 0) { red[wv] = box; red[4 + wv] = cls; }
    __syncthreads();
    if (tid == 0) {
        const float boxT = red[0] + red[1] + red[2] + red[3];
        const float clsT = red[4] + red[5] + red[6] + red[7];
        o[0] = boxT + clsT;   // loss
        o[1] = clsT;          // loss_cls
        o[2] = boxT;          // loss_box
    }
}

extern "C" void kernel_launch(void* const* d_in, const int* in_sizes, int n_in,
                              void* d_out, int out_size, void* d_ws, size_t ws_size,
                              hipStream_t stream)
{
    const float* outp = (const float*)d_in[0];
    const float* tgt  = (const float*)d_in[1];

    char* ws = (char*)d_ws;
    float2* winner   = (float2*)ws;                                    // 512 B
    float*  partials = (float*)(ws + 1024);                            // 2 KiB
    float4* boxes    = (float4*)(ws + 8192);                           // 40 KiB
    float*  gas      = (float*)(ws + 8192 + NB * MAXT * sizeof(float4));

    prep_kernel<<<dim3(NB), dim3(64), 0, stream>>>(outp, tgt, boxes, gas, winner);
    dense_kernel<<<dim3(NPART), dim3(TPB), 0, stream>>>(outp, boxes, gas, partials);
    finalize_kernel<<<1, 256, 0, stream>>>(partials, winner, (float*)d_out);
}